// Round 5
// baseline (215.571 us; speedup 1.0000x reference)
//
#include <hip/hip_runtime.h>
#include <hip/hip_bf16.h>
#include <math.h>

typedef __bf16 bf16x8 __attribute__((ext_vector_type(8)));
typedef float  f32x4  __attribute__((ext_vector_type(4)));

#define BB 2
#define C1 256
#define C2 256
#define HH 64
#define WW 64
#define HW 4096
#define K2 9
#define OCH 27
#define EPSV 1e-5f

// workspace layout (bytes)
#define OM_OFF   0u          // 221184 f32
#define PART_OFF 884736u     // 16*221184 f32
#define WBF_OFF  15040512u   // 589824 bf16
#define WT2_OFF  16220160u   // 65536 f32 (w_off transposed [ic][256])

// ---------------------------------------------------------------------------
// Kernel A: w_dcn fp32 [o][c*9+k] -> bf16 k-major [o][k*256+c].
// ---------------------------------------------------------------------------
__global__ __launch_bounds__(256) void wprep_kernel(
    const float* __restrict__ w, __bf16* __restrict__ wbfT)
{
    int t = blockIdx.x * 256 + threadIdx.x;    // < 589824
    int o = t / 2304;
    int r = t - o * 2304;
    int k = r >> 8;
    int c = r & 255;
    wbfT[t] = (__bf16)w[o * 2304 + c * 9 + k];
}

// ---------------------------------------------------------------------------
// Kernel A2: w_off [oc][ic][k] -> wT [ic][oc*9+k] (row stride 256 f32).
// Makes per-ic weight reads uniform+contiguous -> s_load in offset_partial.
// ---------------------------------------------------------------------------
__global__ __launch_bounds__(256) void wprep2_kernel(
    const float* __restrict__ w_off, float* __restrict__ wT)
{
    int t = blockIdx.x * 256 + threadIdx.x;    // < 62208 = 256*243
    int ic = t / 243;
    int r = t - ic * 243;                      // oc*9+k
    wT[ic * 256 + r] = w_off[(r / 9) * 2304 + ic * 9 + (r % 9)];
}

// ---------------------------------------------------------------------------
// Kernel B: offset conv partials. Weights via SGPR (uniform s_load from wT);
// LDS holds only the 18x18x16 input patch.
// ---------------------------------------------------------------------------
#define ICB 16

__global__ __launch_bounds__(256) void offset_partial_kernel(
    const float* __restrict__ x, const float* __restrict__ wT,
    float* __restrict__ partials)
{
    __shared__ float patch[ICB][324];          // 20736 B

    const int tid  = threadIdx.x;
    const int icc  = blockIdx.x & 15;
    const int tile = blockIdx.x >> 4;
    const int b    = tile >> 4;
    const int t16  = tile & 15;
    const int h0   = (t16 >> 2) * 16;
    const int w0   = (t16 & 3) * 16;

    const float* xb = x + (b * C1 + icc * ICB) * HW;
    for (int i = tid; i < ICB * 324; i += 256) {
        int ic = i / 324, rem = i - ic * 324;
        int r = rem / 18, c = rem - r * 18;
        int hh = h0 - 1 + r, ww = w0 - 1 + c;
        float v = 0.f;
        if (hh >= 0 && hh < HH && ww >= 0 && ww < WW)
            v = xb[ic * HW + hh * WW + ww];
        patch[ic][rem] = v;
    }
    __syncthreads();

    const int r = tid >> 4, c = tid & 15;
    float acc[OCH];
    #pragma unroll
    for (int oc = 0; oc < OCH; oc++) acc[oc] = 0.f;

    for (int ic = 0; ic < ICB; ic++) {
        float nb[9];
        #pragma unroll
        for (int dr = 0; dr < 3; dr++)
            #pragma unroll
            for (int dc = 0; dc < 3; dc++)
                nb[dr * 3 + dc] = patch[ic][(r + dr) * 18 + (c + dc)];
        const float* wp = wT + (icc * ICB + ic) * 256;   // uniform -> s_load
        #pragma unroll
        for (int oc = 0; oc < OCH; oc++) {
            float s = 0.f;
            #pragma unroll
            for (int k = 0; k < 9; k++)
                s += nb[k] * wp[oc * 9 + k];
            acc[oc] += s;
        }
    }

    const int hw = (h0 + r) * WW + (w0 + c);
    float* pb = partials + (size_t)icc * 221184 + (b * OCH) * HW + hw;
    #pragma unroll
    for (int oc = 0; oc < OCH; oc++) pb[oc * HW] = acc[oc];
}

// ---------------------------------------------------------------------------
// Kernel C: reduce 16 partials + bias -> om
// ---------------------------------------------------------------------------
__global__ __launch_bounds__(256) void offset_reduce_kernel(
    const float* __restrict__ partials, const float* __restrict__ b_off,
    float* __restrict__ om)
{
    int t = blockIdx.x * 256 + threadIdx.x;
    int oc = (t >> 12) % OCH;
    float s = b_off[oc];
    #pragma unroll
    for (int i = 0; i < 16; i++) s += partials[i * 221184 + t];
    om[t] = s;
}

// ---------------------------------------------------------------------------
// Kernel D: FUSED gather + MFMA GEMM + BN + SiLU.
// vs round 4: (1) XCD-aware tile swizzle — blocks with bi&7==j cover one
// contiguous 16-row band, so each XCD's L2 holds its x band (1.2 MB) +
// wbfT (1.18 MB); (2) sB uses an XOR chunk swizzle (slot s holds global
// chunk s^(row&7)) killing the 16-way ds_read_b128 bank conflict.
// ---------------------------------------------------------------------------
__global__ __launch_bounds__(256) void fused_kernel(
    const float* __restrict__ x, const float* __restrict__ om,
    const __bf16* __restrict__ wbfT,
    const float* __restrict__ gamma, const float* __restrict__ beta,
    const float* __restrict__ rmean, const float* __restrict__ rvar,
    float* __restrict__ out)
{
    __shared__ __bf16 sA[32 * 72];       // 4608 B, row stride 72 (16B-aligned)
    __shared__ __bf16 sB[256 * 64];      // 32 KB, XOR-swizzled chunks
    __shared__ int    sIdx[32][9][4];
    __shared__ float  sWt[32][9][4];

    const int tid  = threadIdx.x;
    const int wv   = tid >> 6;
    const int lane = tid & 63;
    // XCD swizzle: xcd = bi&7 owns tiles [xcd*32, xcd*32+32) = 16 rows
    const int g = (blockIdx.x & 7) * 32 + (blockIdx.x >> 3);
    const int pixBase = g * 32;
    const int b = pixBase >> 12;
    const int hwBase = pixBase & 4095;
    const int h  = hwBase >> 6;
    const int w0 = hwBase & 63;

    // --- Phase 0: bilinear metadata for 32 pixels x 9 taps ---
    for (int t = tid; t < 32 * 9; t += 256) {
        int p = t / 9, k = t - (t / 9) * 9;
        int hw = hwBase + p;
        const float* omb = om + (size_t)b * OCH * HW;
        float dy  = omb[(2 * k) * HW + hw];
        float dx  = omb[(2 * k + 1) * HW + hw];
        float mmv = omb[(18 + k) * HW + hw];
        mmv = 1.f / (1.f + __expf(-mmv));
        float py = (float)(h - 1 + k / 3) + dy;
        float px = (float)(w0 + p - 1 + k % 3) + dx;
        float y0f = floorf(py), x0f = floorf(px);
        float ly = py - y0f, lx = px - x0f;
        int y0 = (int)y0f, x0 = (int)x0f;
        #pragma unroll
        for (int j = 0; j < 4; j++) {
            int yi = y0 + (j >> 1), xi = x0 + (j & 1);
            bool valid = (yi >= 0) && (yi < HH) && (xi >= 0) && (xi < WW);
            int yc = min(max(yi, 0), HH - 1);
            int xc = min(max(xi, 0), WW - 1);
            sIdx[p][k][j] = (yc * WW + xc) * 4;
            float wy = (j >> 1) ? ly : 1.f - ly;
            float wx = (j & 1) ? lx : 1.f - lx;
            sWt[p][k][j] = valid ? wy * wx * mmv : 0.f;
        }
    }
    __syncthreads();

    const int p   = lane & 31;
    const int ch2 = lane >> 5;
    const int l3  = lane >> 3, l7 = lane & 7;
    const int n15 = lane & 15, q4 = lane >> 4;

    f32x4 acc[2][4];
    #pragma unroll
    for (int i = 0; i < 2; i++)
        #pragma unroll
        for (int j = 0; j < 4; j++)
            acc[i][j] = (f32x4){0.f, 0.f, 0.f, 0.f};

    for (int k = 0; k < 9; k++) {
        const int4   I  = *(const int4*)&sIdx[p][k][0];
        const float4 Wt = *(const float4*)&sWt[p][k][0];

        for (int cc = 0; cc < 4; cc++) {
            // --- stage B chunk (XOR source swizzle: slot l7 <- chunk l7^l3)
            #pragma unroll
            for (int j = 0; j < 8; j++) {
                const char* gp = (const char*)wbfT
                    + ((size_t)(wv * 64 + j * 8 + l3) * 2304 + k * 256 + cc * 64) * 2
                    + ((l7 ^ l3) * 16);
                char* l = (char*)sB + wv * 8192 + j * 1024;
                __builtin_amdgcn_global_load_lds(
                    (const __attribute__((address_space(1))) void*)gp,
                    (__attribute__((address_space(3))) void*)l, 16, 0, 0);
            }

            // --- gather 8 channels into sA row p ---
            const char* sbase = (const char*)x
                + ((size_t)(b * C1 + cc * 64 + wv * 16) << 14);
            bf16x8 v8;
            #pragma unroll
            for (int i = 0; i < 8; i++) {
                const char* cbi = sbase + ((size_t)(ch2 * 8 + i) << 14);
                float v = Wt.x * *(const float*)(cbi + I.x)
                        + Wt.y * *(const float*)(cbi + I.y)
                        + Wt.z * *(const float*)(cbi + I.z)
                        + Wt.w * *(const float*)(cbi + I.w);
                v8[i] = (__bf16)v;
            }
            *(bf16x8*)&sA[p * 72 + wv * 16 + ch2 * 8] = v8;
            __syncthreads();

            // --- MFMA on the 64-K chunk ---
            bf16x8 af[2][2];
            #pragma unroll
            for (int mf = 0; mf < 2; mf++)
                #pragma unroll
                for (int ks = 0; ks < 2; ks++)
                    af[mf][ks] = *(const bf16x8*)&sA[(mf * 16 + n15) * 72 + q4 * 8 + ks * 32];

            #pragma unroll
            for (int nf = 0; nf < 4; nf++) {
                #pragma unroll
                for (int ks = 0; ks < 2; ks++) {
                    int rowB = wv * 64 + nf * 16 + n15;
                    int chunk = (q4 + ks * 4) ^ (n15 & 7);
                    bf16x8 bfr = *(const bf16x8*)((const char*)sB + rowB * 128 + chunk * 16);
                    #pragma unroll
                    for (int mf = 0; mf < 2; mf++)
                        acc[mf][nf] = __builtin_amdgcn_mfma_f32_16x16x32_bf16(
                            af[mf][ks], bfr, acc[mf][nf], 0, 0, 0);
                }
            }
            __syncthreads();
        }
    }

    // --- Epilogue: BN + SiLU ---
    #pragma unroll
    for (int nf = 0; nf < 4; nf++) {
        int o = wv * 64 + nf * 16 + n15;
        float inv = gamma[o] * rsqrtf(rvar[o] + EPSV);
        float sh = beta[o] - rmean[o] * inv;
        #pragma unroll
        for (int mf = 0; mf < 2; mf++) {
            #pragma unroll
            for (int r = 0; r < 4; r++) {
                int m = mf * 16 + q4 * 4 + r;
                float y = acc[mf][nf][r] * inv + sh;
                out[(size_t)((b * C2 + o) << 12) + hwBase + m]
                    = y * (1.f / (1.f + __expf(-y)));
            }
        }
    }
}

// ---------------------------------------------------------------------------
extern "C" void kernel_launch(void* const* d_in, const int* in_sizes, int n_in,
                              void* d_out, int out_size, void* d_ws, size_t ws_size,
                              hipStream_t stream) {
    const float* x      = (const float*)d_in[0];
    const float* w_off  = (const float*)d_in[1];
    const float* b_off  = (const float*)d_in[2];
    const float* w_dcn  = (const float*)d_in[3];
    const float* gamma  = (const float*)d_in[4];
    const float* beta   = (const float*)d_in[5];
    const float* rmean  = (const float*)d_in[6];
    const float* rvar   = (const float*)d_in[7];
    float* out = (float*)d_out;

    char* ws = (char*)d_ws;
    float*  om       = (float*)(ws + OM_OFF);
    float*  partials = (float*)(ws + PART_OFF);
    __bf16* wbfT     = (__bf16*)(ws + WBF_OFF);
    float*  wT       = (float*)(ws + WT2_OFF);

    wprep_kernel<<<2304, 256, 0, stream>>>(w_dcn, wbfT);
    wprep2_kernel<<<243, 256, 0, stream>>>(w_off, wT);
    offset_partial_kernel<<<512, 256, 0, stream>>>(x, wT, partials);
    offset_reduce_kernel<<<864, 256, 0, stream>>>(partials, b_off, om);
    fused_kernel<<<256, 256, 0, stream>>>(x, om, wbfT, gamma, beta,
                                          rmean, rvar, out);
}

// Round 6
// 191.634 us; speedup vs baseline: 1.1249x; 1.1249x over previous
//
#include <hip/hip_runtime.h>
#include <hip/hip_bf16.h>
#include <math.h>

typedef __bf16 bf16x8 __attribute__((ext_vector_type(8)));
typedef float  f32x4  __attribute__((ext_vector_type(4)));

#define BB 2
#define C1 256
#define C2 256
#define HH 64
#define WW 64
#define HW 4096
#define OCH 27
#define EPSV 1e-5f

// workspace layout (bytes)
#define OM_OFF   0u          // 221184 f32 = 884736 B
#define WBF_OFF  884736u     // 589824 bf16 = 1179648 B
#define WOFF_OFF 2064384u    // 73728 bf16 = 147456 B  (total ~2.2 MB)

// ---------------------------------------------------------------------------
// Kernel A: w_dcn fp32 [o][c*9+k] -> bf16 k-major [o][k*256+c].
// ---------------------------------------------------------------------------
__global__ __launch_bounds__(256) void wprep_kernel(
    const float* __restrict__ w, __bf16* __restrict__ wbfT)
{
    int t = blockIdx.x * 256 + threadIdx.x;    // < 589824
    int o = t / 2304;
    int r = t - o * 2304;
    int k = r >> 8;
    int c = r & 255;
    wbfT[t] = (__bf16)w[o * 2304 + c * 9 + k];
}

// ---------------------------------------------------------------------------
// Kernel A2: w_off [oc][ic][k] -> bf16 k-major [32 padded oc][k*256+c].
// Rows 27..31 are zero (N padded to 32 for MFMA).
// ---------------------------------------------------------------------------
__global__ __launch_bounds__(256) void wprep_off_kernel(
    const float* __restrict__ w_off, __bf16* __restrict__ woffB)
{
    int t = blockIdx.x * 256 + threadIdx.x;    // < 73728 = 32*2304
    int o = t / 2304;
    int r = t - o * 2304;
    int k = r >> 8;
    int c = r & 255;
    woffB[t] = (o < OCH) ? (__bf16)w_off[o * 2304 + c * 9 + k] : (__bf16)0.f;
}

// ---------------------------------------------------------------------------
// Kernel B: offset conv via MFMA im2col. Grid 256 (1/CU), block 256.
// M=32 pixels (half image row), N=32 (27+pad), K=2304 split 4 ways across
// waves (9 chunks of 64 each). A im2col direct to fragment registers
// (fixed taps, border-masked); B fragments loaded global->VGPR. No barriers
// in main loop; LDS cross-wave K-reduction + bias at the end.
// ---------------------------------------------------------------------------
__global__ __launch_bounds__(256) void offset_mfma_kernel(
    const float* __restrict__ x, const __bf16* __restrict__ woffB,
    const float* __restrict__ b_off, float* __restrict__ om)
{
    __shared__ float sD[4][32][33];            // 16.9 KB

    const int tid = threadIdx.x, wv = tid >> 6, lane = tid & 63;
    const int g = (blockIdx.x & 7) * 32 + (blockIdx.x >> 3);   // XCD swizzle
    const int pixBase = g * 32;
    const int b = pixBase >> 12;
    const int hwBase = pixBase & 4095;
    const int h = hwBase >> 6, w0 = hwBase & 63;
    const int n15 = lane & 15, q4 = lane >> 4;

    f32x4 acc[2][2];
    #pragma unroll
    for (int i = 0; i < 2; i++)
        #pragma unroll
        for (int j = 0; j < 2; j++)
            acc[i][j] = (f32x4){0.f, 0.f, 0.f, 0.f};

    const float* xb = x + ((size_t)b * C1 << 12);

    for (int i = 0; i < 9; i++) {
        const int kb = wv * 9 + i;             // chunk in [0,36)
        const int k = kb >> 2, cc = kb & 3;
        const int kh = k / 3, kw = k % 3;
        const int hh = h + kh - 1;
        const bool vh = (hh >= 0) && (hh < HH);
        const int hc = min(max(hh, 0), HH - 1);

        bf16x8 af[2][2];
        #pragma unroll
        for (int mf = 0; mf < 2; mf++) {
            const int p = mf * 16 + n15;
            const int ww = w0 + p + kw - 1;
            const bool valid = vh && (ww >= 0) && (ww < WW);
            const int wc = min(max(ww, 0), WW - 1);
            const float* src = xb + hc * WW + wc;
            #pragma unroll
            for (int ks = 0; ks < 2; ks++) {
                bf16x8 a;
                #pragma unroll
                for (int j = 0; j < 8; j++) {
                    int c = cc * 64 + q4 * 8 + ks * 32 + j;
                    float v = src[(size_t)c << 12];
                    a[j] = (__bf16)(valid ? v : 0.f);
                }
                af[mf][ks] = a;
            }
        }

        const __bf16* bp = woffB + k * 256 + cc * 64 + q4 * 8;
        #pragma unroll
        for (int nf = 0; nf < 2; nf++) {
            #pragma unroll
            for (int ks = 0; ks < 2; ks++) {
                bf16x8 bfr = *(const bf16x8*)(bp + (size_t)(nf * 16 + n15) * 2304 + ks * 32);
                #pragma unroll
                for (int mf = 0; mf < 2; mf++)
                    acc[mf][nf] = __builtin_amdgcn_mfma_f32_16x16x32_bf16(
                        af[mf][ks], bfr, acc[mf][nf], 0, 0, 0);
            }
        }
    }

    #pragma unroll
    for (int mf = 0; mf < 2; mf++)
        #pragma unroll
        for (int nf = 0; nf < 2; nf++)
            #pragma unroll
            for (int r = 0; r < 4; r++)
                sD[wv][mf * 16 + q4 * 4 + r][nf * 16 + n15] = acc[mf][nf][r];
    __syncthreads();

    for (int t = tid; t < OCH * 32; t += 256) {
        int oc = t >> 5, m = t & 31;
        float s = b_off[oc] + sD[0][m][oc] + sD[1][m][oc] + sD[2][m][oc] + sD[3][m][oc];
        om[(size_t)b * OCH * HW + oc * HW + hwBase + m] = s;
    }
}

// ---------------------------------------------------------------------------
// Kernel C: FUSED deformable gather + MFMA GEMM + BN + SiLU.
// Grid 256 (1/CU), block 256 = 4 waves. K (2304, tap-major) split 4 ways
// across waves (9 chunks of 64). Gather goes DIRECTLY into A-fragment
// registers (lane (q4,n15) owns pixels {n15,n15+16} x channels q4*8+ks*32+j);
// B fragments loaded global->VGPR (no reuse within block -> LDS staging was
// pure overhead). Main loop barrier-free; LDS reduction + coalesced epilogue.
// ---------------------------------------------------------------------------
__global__ __launch_bounds__(256, 1) void fused_kernel(
    const float* __restrict__ x, const float* __restrict__ om,
    const __bf16* __restrict__ wbfT,
    const float* __restrict__ gamma, const float* __restrict__ beta,
    const float* __restrict__ rmean, const float* __restrict__ rvar,
    float* __restrict__ out)
{
    __shared__ int   sIdx[32][9][4];           // 4.6 KB, byte offsets
    __shared__ float sWt[32][9][4];            // 4.6 KB
    __shared__ float sC[2][32][257];           // 65.8 KB

    const int tid = threadIdx.x, wv = tid >> 6, lane = tid & 63;
    const int g = (blockIdx.x & 7) * 32 + (blockIdx.x >> 3);   // XCD swizzle
    const int pixBase = g * 32;
    const int b = pixBase >> 12;
    const int hwBase = pixBase & 4095;
    const int h = hwBase >> 6, w0 = hwBase & 63;

    // --- Phase 0: bilinear metadata for 32 pixels x 9 taps ---
    for (int t = tid; t < 32 * 9; t += 256) {
        int p = t / 9, k = t - (t / 9) * 9;
        int hw = hwBase + p;
        const float* omb = om + (size_t)b * OCH * HW;
        float dy  = omb[(2 * k) * HW + hw];
        float dx  = omb[(2 * k + 1) * HW + hw];
        float mmv = omb[(18 + k) * HW + hw];
        mmv = 1.f / (1.f + __expf(-mmv));
        float py = (float)(h - 1 + k / 3) + dy;
        float px = (float)(w0 + p - 1 + k % 3) + dx;
        float y0f = floorf(py), x0f = floorf(px);
        float ly = py - y0f, lx = px - x0f;
        int y0 = (int)y0f, x0 = (int)x0f;
        #pragma unroll
        for (int j = 0; j < 4; j++) {
            int yi = y0 + (j >> 1), xi = x0 + (j & 1);
            bool valid = (yi >= 0) && (yi < HH) && (xi >= 0) && (xi < WW);
            int yc = min(max(yi, 0), HH - 1);
            int xc = min(max(xi, 0), WW - 1);
            sIdx[p][k][j] = (yc * WW + xc) * 4;
            float wy = (j >> 1) ? ly : 1.f - ly;
            float wx = (j & 1) ? lx : 1.f - lx;
            sWt[p][k][j] = valid ? wy * wx * mmv : 0.f;
        }
    }
    __syncthreads();

    const int n15 = lane & 15, q4 = lane >> 4;

    f32x4 acc[2][16];                          // [mf][nf] = 128 VGPRs
    #pragma unroll
    for (int i = 0; i < 2; i++)
        #pragma unroll
        for (int j = 0; j < 16; j++)
            acc[i][j] = (f32x4){0.f, 0.f, 0.f, 0.f};

    const char* xb = (const char*)x + ((size_t)b * C1 << 14);

    for (int i = 0; i < 9; i++) {
        const int kb = wv * 9 + i;             // chunk in [0,36)
        const int k = kb >> 2, cc = kb & 3;

        int4 I0 = *(const int4*)&sIdx[n15][k][0];
        float4 W0 = *(const float4*)&sWt[n15][k][0];
        int4 I1 = *(const int4*)&sIdx[16 + n15][k][0];
        float4 W1 = *(const float4*)&sWt[16 + n15][k][0];

        bf16x8 af[2][2];
        #pragma unroll
        for (int ks = 0; ks < 2; ks++) {
            bf16x8 a0, a1;
            #pragma unroll
            for (int j = 0; j < 8; j++) {
                const char* cb = xb + ((size_t)(cc * 64 + q4 * 8 + ks * 32 + j) << 14);
                float v0 = W0.x * *(const float*)(cb + I0.x)
                         + W0.y * *(const float*)(cb + I0.y)
                         + W0.z * *(const float*)(cb + I0.z)
                         + W0.w * *(const float*)(cb + I0.w);
                float v1 = W1.x * *(const float*)(cb + I1.x)
                         + W1.y * *(const float*)(cb + I1.y)
                         + W1.z * *(const float*)(cb + I1.z)
                         + W1.w * *(const float*)(cb + I1.w);
                a0[j] = (__bf16)v0;
                a1[j] = (__bf16)v1;
            }
            af[0][ks] = a0;
            af[1][ks] = a1;
        }

        const __bf16* bp = wbfT + k * 256 + cc * 64 + q4 * 8;
        #pragma unroll
        for (int nf = 0; nf < 16; nf++) {
            #pragma unroll
            for (int ks = 0; ks < 2; ks++) {
                bf16x8 bfr = *(const bf16x8*)(bp + (size_t)(nf * 16 + n15) * 2304 + ks * 32);
                #pragma unroll
                for (int mf = 0; mf < 2; mf++)
                    acc[mf][nf] = __builtin_amdgcn_mfma_f32_16x16x32_bf16(
                        af[mf][ks], bfr, acc[mf][nf], 0, 0, 0);
            }
        }
    }

    // --- Cross-wave K-reduction through LDS ---
    if (wv < 2) {
        #pragma unroll
        for (int mf = 0; mf < 2; mf++)
            #pragma unroll
            for (int nf = 0; nf < 16; nf++)
                #pragma unroll
                for (int r = 0; r < 4; r++)
                    sC[wv][mf * 16 + q4 * 4 + r][nf * 16 + n15] = acc[mf][nf][r];
    }
    __syncthreads();
    if (wv >= 2) {
        const int rg = wv - 2;
        #pragma unroll
        for (int mf = 0; mf < 2; mf++)
            #pragma unroll
            for (int nf = 0; nf < 16; nf++)
                #pragma unroll
                for (int r = 0; r < 4; r++)
                    sC[rg][mf * 16 + q4 * 4 + r][nf * 16 + n15] += acc[mf][nf][r];
    }
    __syncthreads();

    // --- Epilogue: BN + SiLU, coalesced (lanes = consecutive pixels) ---
    const int m = tid & 31, og = tid >> 5;
    float* ob = out + ((size_t)b * C2 << 12) + hwBase + m;
    #pragma unroll
    for (int ii = 0; ii < 32; ii++) {
        int o = og * 32 + ii;
        float s = sC[0][m][o] + sC[1][m][o];
        float inv = gamma[o] * rsqrtf(rvar[o] + EPSV);
        float sh = beta[o] - rmean[o] * inv;
        float y = s * inv + sh;
        ob[(size_t)o << 12] = y * (1.f / (1.f + __expf(-y)));
    }
}

// ---------------------------------------------------------------------------
extern "C" void kernel_launch(void* const* d_in, const int* in_sizes, int n_in,
                              void* d_out, int out_size, void* d_ws, size_t ws_size,
                              hipStream_t stream) {
    const float* x      = (const float*)d_in[0];
    const float* w_off  = (const float*)d_in[1];
    const float* b_off  = (const float*)d_in[2];
    const float* w_dcn  = (const float*)d_in[3];
    const float* gamma  = (const float*)d_in[4];
    const float* beta   = (const float*)d_in[5];
    const float* rmean  = (const float*)d_in[6];
    const float* rvar   = (const float*)d_in[7];
    float* out = (float*)d_out;

    char* ws = (char*)d_ws;
    float*  om    = (float*)(ws + OM_OFF);
    __bf16* wbfT  = (__bf16*)(ws + WBF_OFF);
    __bf16* woffB = (__bf16*)(ws + WOFF_OFF);

    wprep_kernel<<<2304, 256, 0, stream>>>(w_dcn, wbfT);
    wprep_off_kernel<<<288, 256, 0, stream>>>(w_off, woffB);
    offset_mfma_kernel<<<256, 256, 0, stream>>>(x, woffB, b_off, om);
    fused_kernel<<<256, 256, 0, stream>>>(x, om, wbfT, gamma, beta,
                                          rmean, rvar, out);
}

// Round 7
// 155.907 us; speedup vs baseline: 1.3827x; 1.2292x over previous
//
#include <hip/hip_runtime.h>
#include <hip/hip_bf16.h>
#include <math.h>

typedef __bf16 bf16x8 __attribute__((ext_vector_type(8)));
typedef float  f32x4  __attribute__((ext_vector_type(4)));

// 8-byte float pair with 4-byte alignment (gather pair loads)
struct __attribute__((packed, aligned(4))) F2 { float x, y; };

#define BB 2
#define C1 256
#define C2 256
#define HH 64
#define WW 64
#define HW 4096
#define OCH 27
#define EPSV 1e-5f

// workspace layout (bytes)
#define OM_OFF   0u          // 221184 f32 = 884736 B
#define WBF_OFF  884736u     // 589824 bf16 = 1179648 B
#define WOFF_OFF 2064384u    // 73728 bf16 = 147456 B  (total ~2.2 MB)

// ---------------------------------------------------------------------------
// Kernel A: w_dcn fp32 [o][c*9+k] -> bf16 k-major [o][k*256+c].
// ---------------------------------------------------------------------------
__global__ __launch_bounds__(256) void wprep_kernel(
    const float* __restrict__ w, __bf16* __restrict__ wbfT)
{
    int t = blockIdx.x * 256 + threadIdx.x;    // < 589824
    int o = t / 2304;
    int r = t - o * 2304;
    int k = r >> 8;
    int c = r & 255;
    wbfT[t] = (__bf16)w[o * 2304 + c * 9 + k];
}

// ---------------------------------------------------------------------------
// Kernel A2: w_off [oc][ic][k] -> bf16 k-major [32 padded oc][k*256+c].
// ---------------------------------------------------------------------------
__global__ __launch_bounds__(256) void wprep_off_kernel(
    const float* __restrict__ w_off, __bf16* __restrict__ woffB)
{
    int t = blockIdx.x * 256 + threadIdx.x;    // < 73728
    int o = t / 2304;
    int r = t - o * 2304;
    int k = r >> 8;
    int c = r & 255;
    woffB[t] = (o < OCH) ? (__bf16)w_off[o * 2304 + c * 9 + k] : (__bf16)0.f;
}

// ---------------------------------------------------------------------------
// Kernel B: offset conv via MFMA im2col (unchanged from round 6).
// ---------------------------------------------------------------------------
__global__ __launch_bounds__(256) void offset_mfma_kernel(
    const float* __restrict__ x, const __bf16* __restrict__ woffB,
    const float* __restrict__ b_off, float* __restrict__ om)
{
    __shared__ float sD[4][32][33];

    const int tid = threadIdx.x, wv = tid >> 6, lane = tid & 63;
    const int g = (blockIdx.x & 7) * 32 + (blockIdx.x >> 3);
    const int pixBase = g * 32;
    const int b = pixBase >> 12;
    const int hwBase = pixBase & 4095;
    const int h = hwBase >> 6, w0 = hwBase & 63;
    const int n15 = lane & 15, q4 = lane >> 4;

    f32x4 acc[2][2];
    #pragma unroll
    for (int i = 0; i < 2; i++)
        #pragma unroll
        for (int j = 0; j < 2; j++)
            acc[i][j] = (f32x4){0.f, 0.f, 0.f, 0.f};

    const float* xb = x + ((size_t)b * C1 << 12);

    for (int i = 0; i < 9; i++) {
        const int kb = wv * 9 + i;
        const int k = kb >> 2, cc = kb & 3;
        const int kh = k / 3, kw = k % 3;
        const int hh = h + kh - 1;
        const bool vh = (hh >= 0) && (hh < HH);
        const int hc = min(max(hh, 0), HH - 1);

        bf16x8 af[2][2];
        #pragma unroll
        for (int mf = 0; mf < 2; mf++) {
            const int p = mf * 16 + n15;
            const int ww = w0 + p + kw - 1;
            const bool valid = vh && (ww >= 0) && (ww < WW);
            const int wc = min(max(ww, 0), WW - 1);
            const float* src = xb + hc * WW + wc;
            #pragma unroll
            for (int ks = 0; ks < 2; ks++) {
                bf16x8 a;
                #pragma unroll
                for (int j = 0; j < 8; j++) {
                    int c = cc * 64 + q4 * 8 + ks * 32 + j;
                    float v = src[(size_t)c << 12];
                    a[j] = (__bf16)(valid ? v : 0.f);
                }
                af[mf][ks] = a;
            }
        }

        const __bf16* bp = woffB + k * 256 + cc * 64 + q4 * 8;
        #pragma unroll
        for (int nf = 0; nf < 2; nf++) {
            #pragma unroll
            for (int ks = 0; ks < 2; ks++) {
                bf16x8 bfr = *(const bf16x8*)(bp + (size_t)(nf * 16 + n15) * 2304 + ks * 32);
                #pragma unroll
                for (int mf = 0; mf < 2; mf++)
                    acc[mf][nf] = __builtin_amdgcn_mfma_f32_16x16x32_bf16(
                        af[mf][ks], bfr, acc[mf][nf], 0, 0, 0);
            }
        }
    }

    #pragma unroll
    for (int mf = 0; mf < 2; mf++)
        #pragma unroll
        for (int nf = 0; nf < 2; nf++)
            #pragma unroll
            for (int r = 0; r < 4; r++)
                sD[wv][mf * 16 + q4 * 4 + r][nf * 16 + n15] = acc[mf][nf][r];
    __syncthreads();

    for (int t = tid; t < OCH * 32; t += 256) {
        int oc = t >> 5, m = t & 31;
        float s = b_off[oc] + sD[0][m][oc] + sD[1][m][oc] + sD[2][m][oc] + sD[3][m][oc];
        om[(size_t)b * OCH * HW + oc * HW + hwBase + m] = s;
    }
}

// ---------------------------------------------------------------------------
// Kernel C: FUSED gather + MFMA GEMM + BN + SiLU.
// Block = 32 pixels x 256 out, grid 256. Gather lanes = consecutive PIXELS:
// per (pixel,tap) phase 0 precomputes 2 row-pair byte offsets + 4 pre-permuted
// weights (x-clamp folded into weight order) -> inner value = 2 coalesced 8B
// pair loads + 4 FMA. sB triple-buffered (async global_load_lds, XOR bank
// swizzle), sA double-buffered -> ONE barrier per K-chunk.
// ---------------------------------------------------------------------------
__global__ __launch_bounds__(256) void fused_kernel(
    const float* __restrict__ x, const float* __restrict__ om,
    const __bf16* __restrict__ wbfT,
    const float* __restrict__ gamma, const float* __restrict__ beta,
    const float* __restrict__ rmean, const float* __restrict__ rvar,
    float* __restrict__ out)
{
    __shared__ __bf16 sB[3][256 * 64];   // 96 KB
    __shared__ __bf16 sA[2][32 * 72];    // 9.2 KB (row stride 72, 16B-aligned)
    __shared__ int    sOff[9][32][2];    // 2.3 KB
    __shared__ float4 sWt4[9][32];       // 4.6 KB

    const int tid = threadIdx.x, wv = tid >> 6, lane = tid & 63;
    const int g = (blockIdx.x & 7) * 32 + (blockIdx.x >> 3);   // XCD swizzle
    const int pixBase = g * 32;
    const int b = pixBase >> 12;
    const int hwBase = pixBase & 4095;
    const int h = hwBase >> 6, w0 = hwBase & 63;
    const int l3 = lane >> 3, l7 = lane & 7;

    // async B prefetch of chunk kb into buffer buf (wave wv stages 64 rows)
    auto prefetchB = [&](int kb, int buf) {
        const int k = kb >> 2, cc = kb & 3;
        #pragma unroll
        for (int j = 0; j < 8; j++) {
            const char* gp = (const char*)wbfT
                + ((size_t)(wv * 64 + j * 8 + l3) * 2304 + k * 256 + cc * 64) * 2
                + ((l7 ^ l3) * 16);
            char* l = (char*)&sB[buf][0] + wv * 8192 + j * 1024;
            __builtin_amdgcn_global_load_lds(
                (const __attribute__((address_space(1))) void*)gp,
                (__attribute__((address_space(3))) void*)l, 16, 0, 0);
        }
    };

    prefetchB(0, 0);   // overlap with phase 0

    // --- Phase 0: per (pixel,tap) pair offsets + pre-permuted weights ---
    const float* omb = om + (size_t)b * OCH * HW;
    for (int t = tid; t < 288; t += 256) {
        int k = t >> 5, p = t & 31;
        int hw = hwBase + p;
        float dy  = omb[(2 * k) * HW + hw];
        float dx  = omb[(2 * k + 1) * HW + hw];
        float mm  = omb[(18 + k) * HW + hw];
        mm = 1.f / (1.f + __expf(-mm));
        float py = (float)(h - 1 + k / 3) + dy;
        float px = (float)(w0 + p - 1 + k % 3) + dx;
        float y0f = floorf(py), x0f = floorf(px);
        float ly = py - y0f, lx = px - x0f;
        int y0 = (int)y0f, x0 = (int)x0f;
        int r0 = min(max(y0, 0), HH - 1);
        int r1 = min(max(y0 + 1, 0), HH - 1);
        float vy0 = (y0 >= 0 && y0 < HH) ? 1.f : 0.f;
        float vy1 = (y0 + 1 >= 0 && y0 + 1 < HH) ? 1.f : 0.f;
        int xa = min(max(x0, 0), WW - 2);
        float ex0 = (x0 >= 0 && x0 < WW) ? (1.f - lx) : 0.f;
        float ex1 = (x0 + 1 >= 0 && x0 + 1 < WW) ? lx : 0.f;
        int d = x0 - xa;                 // -1 / 0 / +1 (clamped cases)
        float E0, E1;
        if (d == 0)      { E0 = ex0; E1 = ex1; }
        else if (d > 0)  { E0 = 0.f; E1 = ex0; }
        else             { E0 = ex1; E1 = 0.f; }
        float m0 = (1.f - ly) * vy0 * mm, m1 = ly * vy1 * mm;
        sOff[k][p][0] = (r0 * WW + xa) * 4;
        sOff[k][p][1] = (r1 * WW + xa) * 4;
        sWt4[k][p] = (float4){E0 * m0, E1 * m0, E0 * m1, E1 * m1};
    }
    __syncthreads();   // meta visible; also drains prefetch(0)

    const int p   = lane & 31;           // gather pixel
    const int cg  = lane >> 5;           // gather channel half
    const int n15 = lane & 15, q4 = lane >> 4;   // MFMA roles

    f32x4 acc[2][4];
    #pragma unroll
    for (int i = 0; i < 2; i++)
        #pragma unroll
        for (int j = 0; j < 4; j++)
            acc[i][j] = (f32x4){0.f, 0.f, 0.f, 0.f};

    const char* xb = (const char*)x + ((size_t)b * C1 << 14);

    for (int kb = 0; kb < 36; kb++) {
        if (kb < 35) prefetchB(kb + 1, (kb + 1) % 3);

        // --- gather chunk kb -> sA[kb&1] (lanes = pixels, coalesced) ---
        const int k = kb >> 2, cc = kb & 3;
        const int2   off = *(const int2*)&sOff[k][p][0];
        const float4 wt  = sWt4[k][p];
        const char* cb0 = xb + ((size_t)(cc * 64 + wv * 16 + cg * 8) << 14);
        bf16x8 v8;
        #pragma unroll
        for (int j = 0; j < 8; j++) {
            const char* cb = cb0 + ((size_t)j << 14);
            F2 pr0 = *(const F2*)(cb + off.x);
            F2 pr1 = *(const F2*)(cb + off.y);
            v8[j] = (__bf16)(wt.x * pr0.x + wt.y * pr0.y
                           + wt.z * pr1.x + wt.w * pr1.y);
        }
        *(bf16x8*)&sA[kb & 1][p * 72 + wv * 16 + cg * 8] = v8;
        __syncthreads();   // sA ready; prefetch(kb) long since drained

        // --- MFMA on sA[kb&1] x sB[kb%3] ---
        const __bf16* sAb = &sA[kb & 1][0];
        const char*   sBb = (const char*)&sB[kb % 3][0];
        bf16x8 af[2][2];
        #pragma unroll
        for (int mf = 0; mf < 2; mf++)
            #pragma unroll
            for (int ks = 0; ks < 2; ks++)
                af[mf][ks] = *(const bf16x8*)&sAb[(mf * 16 + n15) * 72 + q4 * 8 + ks * 32];
        #pragma unroll
        for (int nf = 0; nf < 4; nf++) {
            #pragma unroll
            for (int ks = 0; ks < 2; ks++) {
                int rowB = wv * 64 + nf * 16 + n15;
                int ck = (q4 + ks * 4) ^ (n15 & 7);
                bf16x8 bfr = *(const bf16x8*)(sBb + rowB * 128 + ck * 16);
                #pragma unroll
                for (int mf = 0; mf < 2; mf++)
                    acc[mf][nf] = __builtin_amdgcn_mfma_f32_16x16x32_bf16(
                        af[mf][ks], bfr, acc[mf][nf], 0, 0, 0);
            }
        }
        // no second barrier: sA double-buffered, sB triple-buffered
    }

    // --- Epilogue: BN + SiLU (C/D layout: col=o, row=pixel) ---
    #pragma unroll
    for (int nf = 0; nf < 4; nf++) {
        int o = wv * 64 + nf * 16 + n15;
        float inv = gamma[o] * rsqrtf(rvar[o] + EPSV);
        float sh = beta[o] - rmean[o] * inv;
        #pragma unroll
        for (int mf = 0; mf < 2; mf++) {
            #pragma unroll
            for (int r = 0; r < 4; r++) {
                int m = mf * 16 + q4 * 4 + r;
                float y = acc[mf][nf][r] * inv + sh;
                out[(size_t)((b * C2 + o) << 12) + hwBase + m]
                    = y * (1.f / (1.f + __expf(-y)));
            }
        }
    }
}

// ---------------------------------------------------------------------------
extern "C" void kernel_launch(void* const* d_in, const int* in_sizes, int n_in,
                              void* d_out, int out_size, void* d_ws, size_t ws_size,
                              hipStream_t stream) {
    const float* x      = (const float*)d_in[0];
    const float* w_off  = (const float*)d_in[1];
    const float* b_off  = (const float*)d_in[2];
    const float* w_dcn  = (const float*)d_in[3];
    const float* gamma  = (const float*)d_in[4];
    const float* beta   = (const float*)d_in[5];
    const float* rmean  = (const float*)d_in[6];
    const float* rvar   = (const float*)d_in[7];
    float* out = (float*)d_out;

    char* ws = (char*)d_ws;
    float*  om    = (float*)(ws + OM_OFF);
    __bf16* wbfT  = (__bf16*)(ws + WBF_OFF);
    __bf16* woffB = (__bf16*)(ws + WOFF_OFF);

    wprep_kernel<<<2304, 256, 0, stream>>>(w_dcn, wbfT);
    wprep_off_kernel<<<288, 256, 0, stream>>>(w_off, woffB);
    offset_mfma_kernel<<<256, 256, 0, stream>>>(x, woffB, b_off, om);
    fused_kernel<<<256, 256, 0, stream>>>(x, om, wbfT, gamma, beta,
                                          rmean, rvar, out);
}